// Round 11
// baseline (620.946 us; speedup 1.0000x reference)
//
#include <hip/hip_runtime.h>

typedef _Float16 half8 __attribute__((ext_vector_type(8)));
typedef float floatx4 __attribute__((ext_vector_type(4)));

#define LBF 2304   // Lb == Lf
#define K1  1152
#define LDK2 2304  // worst-case compacted stride (Kc can be up to 2304)

__device__ __forceinline__ void gll16(const _Float16* g, _Float16* l) {
    __builtin_amdgcn_global_load_lds((const __attribute__((address_space(1))) void*)g,
                                     (__attribute__((address_space(3))) void*)l, 16, 0, 0);
}

// decode Kc from signed pos'[2303] (excl-scan encoding: valid->e, masked->-e-1)
__device__ __forceinline__ int dec_kc(int s) { return (s >= 0) ? s + 1 : -s - 1; }

// ---------------- stage ds (blocks 0..9215) + mask scan (block 9216) ----------
__global__ void stage_scan(const float* __restrict__ f, const float* __restrict__ bsrc,
                           const float* __restrict__ mask,
                           float* __restrict__ ds, int* __restrict__ pos) {
    int tid = threadIdx.x;
    if (blockIdx.x < 9216) {
        long flat = (long)blockIdx.x * 256 + tid;   // [0, 2*4*128*2304)
        int p = flat % 2304;
        long rest = flat / 2304;
        int c = rest % 128;
        int b = (rest / 128) % 4;
        int t = rest / (128 * 4);
        int pi = p / 48, pj = p % 48;
        const float* src = t ? bsrc : f;
        ds[flat] = src[(((long)b * 128 + c) * 96 + 2 * pi) * 96 + 2 * pj];
        return;
    }
    // ---- scan block: mask -> signed compaction index pos' ----
    int mmb[9], loc[9]; int s = 0;
#pragma unroll
    for (int t = 0; t < 9; t++) {
        int p = tid * 9 + t;
        int pi = p / 48, pj = p % 48;
        float sm = 0.f;
#pragma unroll
        for (int u = 0; u < 3; u++)
#pragma unroll
            for (int v = 0; v < 3; v++) {
                int y = pi - 1 + u, x = pj - 1 + v;
                if ((unsigned)y < 48u && (unsigned)x < 48u)
                    sm += mask[(8 * y) * 384 + 8 * x];
            }
        int m = (sm == 0.f) ? 1 : 0;
        mmb[t] = m; loc[t] = s; s += m;
    }
    __shared__ int sh[256];
    sh[tid] = s; __syncthreads();
    for (int off = 1; off < 256; off <<= 1) {
        int v = (tid >= off) ? sh[tid - off] : 0;
        __syncthreads();
        sh[tid] += v;
        __syncthreads();
    }
    int excl = sh[tid] - s;
#pragma unroll
    for (int t = 0; t < 9; t++) {
        int e = excl + loc[t];
        pos[tid * 9 + t] = mmb[t] ? e : (-e - 1);
    }
}

// ---------------- prep: fp patches (x<9) + wn normalized patches (x==9) -------
__global__ void prep_fpwn(const float* __restrict__ ds, _Float16* __restrict__ fp,
                          _Float16* __restrict__ wn) {
    int p = blockIdx.y;                       // [0,2304)
    int b = blockIdx.z;
    int tid = threadIdx.x;                    // 128
    int pi = p / 48, pj = p % 48;
    if (blockIdx.x < 9) {
        int k = blockIdx.x * 128 + tid;       // [0,1152)
        int c = k / 9, r = k % 9, u = r / 3, v = r % 3;
        int y = pi - 1 + u, x = pj - 1 + v;
        float val = 0.f;
        if ((unsigned)y < 48u && (unsigned)x < 48u)
            val = ds[((long)(b * 128 + c)) * 2304 + y * 48 + x];
        fp[((long)b * LBF + p) * K1 + k] = (_Float16)val;
        return;
    }
    // wn role
    const float* dsb = ds + (long)(4 + b) * 128 * 2304;
    float w[9];
    float ss = 0.f;
#pragma unroll
    for (int t = 0; t < 9; t++) {
        int k = tid + t * 128;
        int c = k / 9, r = k % 9, u = r / 3, v = r % 3;
        int y = pi - 1 + u, x = pj - 1 + v;
        float val = 0.f;
        if ((unsigned)y < 48u && (unsigned)x < 48u)
            val = dsb[(long)c * 2304 + y * 48 + x];
        w[t] = val;
        ss += val * val;
    }
    for (int m = 32; m; m >>= 1) ss += __shfl_xor(ss, m);
    __shared__ float sh[2];
    if ((tid & 63) == 0) sh[tid >> 6] = ss;
    __syncthreads();
    float denom = sqrtf(sh[0] + sh[1] + 0.1152f);  // sum(w^2 + ESC)
    float inv = 1.f / denom;
#pragma unroll
    for (int t = 0; t < 9; t++) {
        int k = tid + t * 128;
        wn[((long)b * LBF + p) * K1 + k] = (_Float16)(w[t] * inv);
    }
}

// ---------------- prep: compacted Wt, line-efficient ---------------------------
__global__ void prep_wtc(const float* __restrict__ bsrc, const int* __restrict__ pos,
                         _Float16* __restrict__ wtc) {
    int p = blockIdx.x * 256 + threadIdx.x;   // [0,2304)
    int c = blockIdx.y;                       // [0,128)
    int b = blockIdx.z;
    int sp = pos[p];
    long base = ((long)b * 2048 + c * 16) * LDK2;
    if (sp < 0) {
        int kc = dec_kc(pos[2303]);
        int kp = (kc + 63) & ~63;
        int mo = p + sp + 1;                  // masked ordinal
        if (mo < kp - kc) {
#pragma unroll
            for (int n = 0; n < 16; n++)
                wtc[base + (long)n * LDK2 + kc + mo] = (_Float16)0.f;
        }
        return;
    }
    int pi = p / 48, pj = p % 48;
    const float* src = bsrc + ((long)b * 128 + c) * 96 * 96;
#pragma unroll
    for (int u = 0; u < 4; u++) {
        int y = 2 * pi - 1 + u;
        bool yok = (unsigned)y < 96u;
#pragma unroll
        for (int v = 0; v < 4; v++) {
            int x = 2 * pj - 1 + v;
            float val = 0.f;
            if (yok && (unsigned)x < 96u) val = src[y * 96 + x];
            wtc[base + (long)(u * 4 + v) * LDK2 + sp] = (_Float16)val;
        }
    }
}

// ---------------- NT GEMM, BK=64, double-buffered LDS (R6 winner) -------------
__device__ __forceinline__ void gemm_compute(const _Float16* lA, const _Float16* lB,
                                             floatx4 (&acc)[4][4],
                                             int wr, int wc, int lm, int pcp) {
    half8 af[4], bf[4];
#pragma unroll
    for (int t = 0; t < 4; t++) {
        af[t] = *(const half8*)&lA[(wr * 64 + t * 16 + lm) * 64 + pcp];
        bf[t] = *(const half8*)&lB[(wc * 64 + t * 16 + lm) * 64 + pcp];
    }
#pragma unroll
    for (int i = 0; i < 4; i++)
#pragma unroll
        for (int j = 0; j < 4; j++)
            acc[i][j] = __builtin_amdgcn_mfma_f32_16x16x32_f16(af[i], bf[j], acc[i][j], 0, 0, 0);
#pragma unroll
    for (int t = 0; t < 4; t++) {
        af[t] = *(const half8*)&lA[(wr * 64 + t * 16 + lm) * 64 + (pcp ^ 32)];
        bf[t] = *(const half8*)&lB[(wc * 64 + t * 16 + lm) * 64 + (pcp ^ 32)];
    }
#pragma unroll
    for (int i = 0; i < 4; i++)
#pragma unroll
        for (int j = 0; j < 4; j++)
            acc[i][j] = __builtin_amdgcn_mfma_f32_16x16x32_f16(af[i], bf[j], acc[i][j], 0, 0, 0);
}

__global__ __launch_bounds__(256)
void gemm_nt64(const _Float16* __restrict__ A, const _Float16* __restrict__ B,
               float* __restrict__ C, int M, int N, int ldk, int swapxy,
               const int* __restrict__ Kpos, int Kstat, long sA, long sB, long sC) {
    A += blockIdx.z * sA; B += blockIdx.z * sB; C += blockIdx.z * sC;
    int K;
    if (Kpos) { int kc = dec_kc(Kpos[0]); K = (kc + 63) & ~63; }
    else K = Kstat;
    const int tid = threadIdx.x;
    const int lane = tid & 63, wave = tid >> 6;
    const int wr = wave >> 1, wc = wave & 1;
    const int bm = swapxy ? blockIdx.x : blockIdx.y;
    const int bn = swapxy ? blockIdx.y : blockIdx.x;
    const int m0 = bm * 128, n0 = bn * 128;

    __shared__ _Float16 sm[4][128 * 64];   // [buf*2 + (A=0/B=1)]: 4 x 16 KB

    floatx4 acc[4][4] = {};

    const int lm = lane & 15, q = lane >> 4;
    const int pcp = (q ^ (lm & 7)) * 8;      // substep-0 phys offset (halves)

    const int srow8 = lane >> 3;
    const int gc = ((lane & 7) ^ srow8) * 8;  // global halves offset (XOR swizzle)
    const _Float16* gA[4]; const _Float16* gB[4];
    int dOff[4];
#pragma unroll
    for (int c = 0; c < 4; c++) {
        int r = (wave * 4 + c) * 8 + srow8;
        gA[c] = A + (long)(m0 + r) * ldk + gc;
        gB[c] = B + (long)(n0 + r) * ldk + gc;
        dOff[c] = (wave * 4 + c) * 512;
    }

    if (K > 0) {
#pragma unroll
        for (int c = 0; c < 4; c++) gll16(gA[c], &sm[0][dOff[c]]);
#pragma unroll
        for (int c = 0; c < 4; c++) gll16(gB[c], &sm[1][dOff[c]]);
        __syncthreads();
        int k0 = 0, buf = 0;
        while (true) {
            int kn = k0 + 64;
            if (kn < K) {
                const int nb = (buf ^ 1) * 2;
#pragma unroll
                for (int c = 0; c < 4; c++) gll16(gA[c] + kn, &sm[nb][dOff[c]]);
#pragma unroll
                for (int c = 0; c < 4; c++) gll16(gB[c] + kn, &sm[nb + 1][dOff[c]]);
            }
            gemm_compute(sm[buf * 2], sm[buf * 2 + 1], acc, wr, wc, lm, pcp);
            __syncthreads();
            k0 = kn; buf ^= 1;
            if (k0 >= K) break;
        }
    }

    // C/D layout: col = lane&15, row = (lane>>4)*4 + reg   [m89-verified]
    const int col = n0 + wc * 64 + lm;
    const int rowq = q * 4;
#pragma unroll
    for (int i = 0; i < 4; i++) {
        int row = m0 + wr * 64 + i * 16 + rowq;
#pragma unroll
        for (int j = 0; j < 4; j++)
#pragma unroll
            for (int r = 0; r < 4; r++)
                C[(long)(row + r) * N + col + j * 16] = acc[i][j][r];
    }
}

// ---------------- fused double-diag 9-tap + softmax, LDS-staged ---------------
// Same algebra as R9 (correctness-validated); taps now read LDS.
// 9 block-uniform rows; main col window per phase + fixed edge strips for the
// digit-carry taps (left cols [0,48], right cols [2255,2303]).
#define FS_TAPS(ubase, ucnt, MBASE)                                            \
    _Pragma("unroll")                                                          \
    for (int u = (ubase); u < (ubase) + (ucnt); u++) {                         \
        int x = tid + u * 256;                                                 \
        int sp = pos[x];                                                       \
        ps[u] = sp;                                                            \
        float xv = 0.f;                                                        \
        if (sp >= 0) {                                                         \
            int a = x / 48, b = x - a * 48;                                    \
            float acc = 0.f;                                                   \
            _Pragma("unroll")                                                  \
            for (int t = 0; t < 3; t++) {                                      \
                int d2 = t - 1, ad = a + d2;                                   \
                if ((unsigned)ad < 48u) {                                      \
                    int c = x + 48 * d2;                                       \
                    _Pragma("unroll")                                          \
                    for (int s = 0; s < 3; s++) {                              \
                        int cc = c + s - 1;                                    \
                        if (rok[t * 3 + s] && (unsigned)cc < 2304u)            \
                            acc += lmain[t * 3 + s][cc - (MBASE)];             \
                    }                                                          \
                } else if (ad == 48) {                                         \
                    if (b < 47) {                                              \
                        _Pragma("unroll")                                      \
                        for (int s = 0; s < 3; s++) {                          \
                            int cc = b + s;                                    \
                            if (rok[t * 3 + s]) acc += lleft[t * 3 + s][cc];   \
                        }                                                      \
                    }                                                          \
                } else {                                                       \
                    if (b > 0) {                                               \
                        _Pragma("unroll")                                      \
                        for (int s = 0; s < 3; s++) {                          \
                            int cc = 2255 + b + s - 1;                         \
                            if (rok[t * 3 + s]) acc += lright[t * 3 + s][cc - 2240]; \
                        }                                                      \
                    }                                                          \
                }                                                              \
            }                                                                  \
            xv = acc * 10.f;                                                   \
        }                                                                      \
        v[u] = xv;                                                             \
        mx = fmaxf(mx, xv);                                                    \
    }

__global__ __launch_bounds__(256)
void fuse_softmax(const float* __restrict__ ST_, const int* __restrict__ pos,
                  _Float16* __restrict__ attTc) {
    int j = blockIdx.x, bb = blockIdx.y;
    int tid = threadIdx.x;
    const float* S = ST_ + (long)bb * LBF * LBF;
    _Float16* orow = attTc + ((long)bb * LBF + j) * LDK2;

    __shared__ float lmain[9][1408];   // 50688 B
    __shared__ float lleft[9][64];     //  2304 B
    __shared__ float lright[9][64];    //  2304 B
    __shared__ long  s_rbase[9];
    __shared__ int   s_rokf[9];
    __shared__ float sh[4], sh2[4];

    // block-uniform row set (9 rows) via digit algebra
    int aj = j / 48, bj = j - aj * 48;
    bool rok[9];
    if (tid < 9) {
        int t = tid / 3, s = tid - t * 3;
        int d2 = t - 1, ad = aj + d2;
        bool jok; int y0;
        if ((unsigned)ad < 48u) { jok = true;    y0 = j + 48 * d2; }
        else if (ad == 48)      { jok = bj < 47; y0 = bj + 1; }
        else                    { jok = bj > 0;  y0 = 2255 + bj; }
        int y = y0 + s - 1;
        bool ok = jok && (unsigned)y < (unsigned)LBF;
        s_rokf[tid] = ok ? 1 : 0;
        s_rbase[tid] = (long)(ok ? y : 0) * LBF;
    }
    __syncthreads();
#pragma unroll
    for (int r = 0; r < 9; r++) rok[r] = (s_rokf[r] != 0);

    // load edge strips (once) + main window phase 0: cols [0, 1408)
    for (int idx = tid; idx < 9 * 32; idx += 256) {
        int r = idx >> 5, e = idx & 31;
        int col = (e < 16) ? (e * 4) : (2240 + (e - 16) * 4);
        float4 w = {0.f, 0.f, 0.f, 0.f};
        if (s_rokf[r]) w = *(const float4*)&S[s_rbase[r] + col];
        if (e < 16) *(float4*)&lleft[r][e * 4] = w;
        else        *(float4*)&lright[r][(e - 16) * 4] = w;
    }
    for (int idx = tid; idx < 9 * 352; idx += 256) {
        int r = idx / 352, c4 = idx - r * 352;
        int col = c4 * 4;
        float4 w = {0.f, 0.f, 0.f, 0.f};
        if (s_rokf[r]) w = *(const float4*)&S[s_rbase[r] + col];
        *(float4*)&lmain[r][c4 * 4] = w;
    }
    __syncthreads();

    float v[9]; int ps[9];
    float mx = -1e30f;
    FS_TAPS(0, 4, 0)          // phase 0: x in [0,1024), taps cc <= 1073
    __syncthreads();          // all waves done with phase-0 window

    // main window phase 1: cols [960, 2304)
    for (int idx = tid; idx < 9 * 352; idx += 256) {
        int r = idx / 352, c4 = idx - r * 352;
        int col = 960 + c4 * 4;
        float4 w = {0.f, 0.f, 0.f, 0.f};
        if (s_rokf[r] && col < 2304) w = *(const float4*)&S[s_rbase[r] + col];
        *(float4*)&lmain[r][c4 * 4] = w;
    }
    __syncthreads();
    FS_TAPS(4, 5, 960)        // phase 1: x in [1024,2304), taps cc >= 975

    for (int m = 32; m; m >>= 1) mx = fmaxf(mx, __shfl_xor(mx, m));
    if ((tid & 63) == 0) sh[tid >> 6] = mx;
    __syncthreads();
    mx = fmaxf(fmaxf(sh[0], sh[1]), fmaxf(sh[2], sh[3]));
    float sum = 0.f;
#pragma unroll
    for (int u = 0; u < 9; u++) { v[u] = __expf(v[u] - mx); sum += v[u]; }
    for (int m = 32; m; m >>= 1) sum += __shfl_xor(sum, m);
    if ((tid & 63) == 0) sh2[tid >> 6] = sum;
    __syncthreads();
    sum = sh2[0] + sh2[1] + sh2[2] + sh2[3];
    float inv = 1.f / sum;
#pragma unroll
    for (int u = 0; u < 9; u++) {
        if (ps[u] >= 0) orow[ps[u]] = (_Float16)(v[u] * inv);
    }
    int kc = dec_kc(pos[2303]);
    int kp = (kc + 63) & ~63;
    if (tid < kp - kc) orow[kc + tid] = (_Float16)0.f;
}

// ---------------- scatter from MT[n][p]: coalesced transposed-conv gather -----
__global__ void scatter_out(const float* __restrict__ MT_, float* __restrict__ out) {
    int yx = blockIdx.x * 256 + threadIdx.x;  // [0, 9216)
    int c = blockIdx.y, b = blockIdx.z;
    int y = yx / 96, x = yx % 96;
    const float* Mb = MT_ + (long)b * 2048 * LBF;
    float s = 0.f;
    for (int uu = (y + 1) & 1; uu < 4; uu += 2) {
        int fi = (y + 1 - uu) >> 1;
        if ((unsigned)fi >= 48u) continue;
        for (int vv = (x + 1) & 1; vv < 4; vv += 2) {
            int fj = (x + 1 - vv) >> 1;
            if ((unsigned)fj >= 48u) continue;
            s += Mb[(long)(c * 16 + uu * 4 + vv) * LBF + fi * 48 + fj];
        }
    }
    out[(((long)b * 128 + c) * 96 + y) * 96 + x] = 0.25f * s;
}

extern "C" void kernel_launch(void* const* d_in, const int* in_sizes, int n_in,
                              void* d_out, int out_size, void* d_ws, size_t ws_size,
                              hipStream_t stream) {
    const float* f    = (const float*)d_in[0];
    const float* bsrc = (const float*)d_in[1];
    const float* mask = (const float*)d_in[2];
    float* out = (float*)d_out;

    char* ws = (char*)d_ws;
    const size_t offR1  = 84934656;
    const size_t offWn  = offR1 + 21233664;
    const size_t offWtc = offR1 + 42467328;
    const size_t offDs  = offWtc + 37748736;          // 165150720 (ds 9.4 MB)
    const size_t offPos = offDs + 2ul * 21233664;     // 207618048
    const size_t NEED   = offPos + 9216;              // 207627264
    if (ws_size < NEED) return;  // visible failure, no OOB writes

    float*    ST    = (float*)(ws + 0);
    float*    MT    = (float*)(ws + 0);
    _Float16* fp    = (_Float16*)(ws + offR1);
    _Float16* wn    = (_Float16*)(ws + offWn);
    _Float16* attTc = (_Float16*)(ws + offR1);
    _Float16* Wtc   = (_Float16*)(ws + offWtc);
    float*    ds    = (float*)(ws + offDs);
    int*      pos   = (int*)(ws + offPos);

    stage_scan<<<dim3(9217), 256, 0, stream>>>(f, bsrc, mask, ds, pos);
    prep_fpwn<<<dim3(10, 2304, 4), 128, 0, stream>>>(ds, fp, wn);
    prep_wtc<<<dim3(9, 128, 4), 256, 0, stream>>>(bsrc, pos, Wtc);

    // GEMM1: ST[j,i] = sum_k fp[j,k] * wn[i,k]  (static K=1152)
    gemm_nt64<<<dim3(18, 18, 4), 256, 0, stream>>>(fp, wn, ST, 2304, 2304, K1, 0,
        nullptr, K1, (long)2304 * K1, (long)2304 * K1, (long)2304 * 2304);

    // fused double-diag + softmax + compaction (LDS-staged taps)
    fuse_softmax<<<dim3(LBF, 4), 256, 0, stream>>>(ST, pos, attTc);

    // GEMM2 transposed output, R4 block-order: x sweeps Wtc (A), y pins attTc (B)
    gemm_nt64<<<dim3(16, 18, 4), 256, 0, stream>>>(Wtc, attTc, MT, 2048, 2304, LDK2, 1,
        pos + 2303, 0, (long)2048 * LDK2, (long)2304 * LDK2, (long)2048 * 2304);

    scatter_out<<<dim3(36, 128, 4), 256, 0, stream>>>(MT, out);
}